// Round 6
// baseline (14581.593 us; speedup 1.0000x reference)
//
#include <hip/hip_runtime.h>
#include <hip/hip_bf16.h>
#include <math.h>
#include <stdint.h>

#define BATCH 8
#define SEQ   1024
#define DIM   768
#define HEADS 12
#define DHEAD 64
#define TOK   (BATCH*SEQ)      // 8192 rows
#define INNER 768
#define FFDIM 3072
#define QKVN  2304

// ---- bf16 helpers (raw uint16 storage) ----
__device__ __forceinline__ float b2f(uint16_t u) {
    return __uint_as_float(((uint32_t)u) << 16);
}
__device__ __forceinline__ uint16_t f2b(float f) {
    uint32_t x = __float_as_uint(f);
    x += 0x7fffu + ((x >> 16) & 1u);   // RNE
    return (uint16_t)(x >> 16);
}

// ---- naive LayerNorm: one wave (64 threads) per row of 768, fp32 in, bf16 out ----
__global__ __launch_bounds__(64) void ln_naive(
    const float* __restrict__ x, const float* __restrict__ g,
    const float* __restrict__ be, uint16_t* __restrict__ y)
{
    const int lane = threadIdx.x;
    const size_t row = blockIdx.x;
    float v[12];
    float s = 0.f, ss = 0.f;
    #pragma unroll
    for (int j = 0; j < 12; j++) {
        int idx = lane + j * 64;
        float f = x[row * DIM + idx];
        v[j] = f; s += f; ss += f * f;
    }
    #pragma unroll
    for (int off = 32; off > 0; off >>= 1) {
        s  += __shfl_xor(s, off);
        ss += __shfl_xor(ss, off);
    }
    const float mu = s * (1.f / DIM);
    const float var = ss * (1.f / DIM) - mu * mu;
    const float rstd = rsqrtf(var + 1e-5f);
    #pragma unroll
    for (int j = 0; j < 12; j++) {
        int idx = lane + j * 64;
        y[row * DIM + idx] = f2b((v[j] - mu) * rstd * g[idx] + be[idx]);
    }
}

// ---- naive GEMM: C[m][n] = act(sum_k bf16(A[m][k]) * B_fp32[k][n] + bias) ----
// One thread per output column n (blocks of 256 n), 4 rows m per thread.
// RES: fp32 residual (stride ldc). OUTF: write fp32, else bf16.
template<bool BIAS, bool GELU, bool RES, bool OUTF>
__global__ __launch_bounds__(256) void gemm_naive(
    const uint16_t* __restrict__ A, const float* __restrict__ B,
    void* C, const float* __restrict__ bias, int bias_off,
    const float* __restrict__ res, int K, int lda, int ldb, int ldc)
{
    const int n = blockIdx.x * 256 + threadIdx.x;
    const int m0 = blockIdx.y * 4;
    float acc[4] = {0.f, 0.f, 0.f, 0.f};
    for (int k = 0; k < K; k++) {
        float bv = B[(size_t)k * ldb + n];
        #pragma unroll
        for (int i = 0; i < 4; i++)
            acc[i] += b2f(A[(size_t)(m0 + i) * lda + k]) * bv;
    }
    float bvv = BIAS ? bias[bias_off + n] : 0.f;
    #pragma unroll
    for (int i = 0; i < 4; i++) {
        float v = acc[i] + bvv;
        if (GELU) v = 0.5f * v * (1.f + erff(v * 0.70710678118f));
        size_t ci = (size_t)(m0 + i) * ldc + n;
        if (RES) v += res[ci];
        if (OUTF) ((float*)C)[ci] = v;
        else      ((uint16_t*)C)[ci] = f2b(v);
    }
}

// ---- naive attention: one wave per (q-row, head, batch); online softmax ----
// qkv[TOK][2304] bf16: cols [0,768) Q, [768,1536) K, [1536,2304) V.
// Output written in-place into this row's Q slot (disjoint across blocks;
// no block reads another block's Q slot).
__global__ __launch_bounds__(64) void attn_naive(uint16_t* qkv)
{
    const int lane = threadIdx.x;               // d within head
    const int q = blockIdx.x, h = blockIdx.y, b = blockIdx.z;
    const size_t row = (size_t)b * SEQ + q;
    const int hc = h * DHEAD + lane;

    const float qd = b2f(qkv[row * QKVN + hc]) * 0.125f;   // scale = 1/sqrt(64)
    float m = -1e30f, l = 0.f, O = 0.f;
    for (int kk = 0; kk < SEQ; kk++) {
        const size_t krow = (size_t)b * SEQ + kk;
        float p = qd * b2f(qkv[krow * QKVN + INNER + hc]);
        #pragma unroll
        for (int off = 32; off > 0; off >>= 1) p += __shfl_xor(p, off);
        // p = full dot(q,k)*scale on all lanes
        const float vd = b2f(qkv[krow * QKVN + 2 * INNER + hc]);
        const float mn = fmaxf(m, p);
        const float al = __expf(m - mn);
        const float pe = __expf(p - mn);
        l = l * al + pe;
        O = O * al + pe * vd;
        m = mn;
    }
    qkv[row * QKVN + hc] = f2b(O / l);
}

extern "C" void kernel_launch(void* const* d_in, const int* in_sizes, int n_in,
                              void* d_out, int out_size, void* d_ws, size_t ws_size,
                              hipStream_t stream) {
    const float* x      = (const float*)d_in[0];   // [8192][768] fp32
    const float* ln1_g  = (const float*)d_in[1];
    const float* ln1_b  = (const float*)d_in[2];
    const float* ln2_g  = (const float*)d_in[3];
    const float* ln2_b  = (const float*)d_in[4];
    const float* w_qkv  = (const float*)d_in[5];   // [768][2304]
    const float* w_out  = (const float*)d_in[6];   // [768][768]
    const float* b_out  = (const float*)d_in[7];
    const float* w_ff1  = (const float*)d_in[8];   // [768][3072]
    const float* b_ff1  = (const float*)d_in[9];
    const float* w_ff2  = (const float*)d_in[10];  // [3072][768]
    const float* b_ff2  = (const float*)d_in[11];
    float* out = (float*)d_out;                    // [8192][768] fp32 (reference output dtype)

    // ws (uint16 elements), total 50.3 MB:
    uint16_t* ws  = (uint16_t*)d_ws;
    uint16_t* qkv = ws;                            // [8192][2304] bf16
    uint16_t* ffc = ws;                            // [8192][1536] bf16 (reuses dead qkv)
    uint16_t* h   = ws + (size_t)TOK * QKVN;       // [8192][768] bf16

    // h = LN1(x)
    hipLaunchKernelGGL(ln_naive, dim3(TOK), dim3(64), 0, stream, x, ln1_g, ln1_b, h);
    // qkv = h @ w_qkv  (bf16 out)
    hipLaunchKernelGGL((gemm_naive<false, false, false, false>), dim3(QKVN / 256, TOK / 4), dim3(256), 0, stream,
                       h, w_qkv, qkv, nullptr, 0, nullptr, DIM, DIM, QKVN, QKVN);
    // attention in-place (O -> Q slots)
    hipLaunchKernelGGL(attn_naive, dim3(SEQ, HEADS, BATCH), dim3(64), 0, stream, qkv);
    // d_out(fp32) = x + attnO @ w_out + b_out   (A = qkv Q-slots, lda=2304)
    hipLaunchKernelGGL((gemm_naive<true, false, true, true>), dim3(DIM / 256, TOK / 4), dim3(256), 0, stream,
                       qkv, w_out, out, b_out, 0, x, INNER, QKVN, DIM, DIM);
    // h = LN2(d_out fp32)
    hipLaunchKernelGGL(ln_naive, dim3(TOK), dim3(64), 0, stream, out, ln2_g, ln2_b, h);
    // FFN in two hidden chunks of 1536 (ffc reuses dead qkv region)
    for (int c = 0; c < 2; c++) {
        // ffc = gelu(h @ w_ff1[:, c*1536:+1536] + b_ff1[c*1536:])  (bf16 out)
        hipLaunchKernelGGL((gemm_naive<true, true, false, false>), dim3(1536 / 256, TOK / 4), dim3(256), 0, stream,
                           h, w_ff1 + (size_t)c * 1536, ffc, b_ff1, c * 1536, nullptr,
                           DIM, DIM, FFDIM, 1536);
        // d_out += ffc @ w_ff2[c*1536:+1536, :] (+ b_ff2 on first chunk), fp32 in-place
        if (c == 0) {
            hipLaunchKernelGGL((gemm_naive<true, false, true, true>), dim3(DIM / 256, TOK / 4), dim3(256), 0, stream,
                               ffc, w_ff2 + (size_t)c * 1536 * DIM, out, b_ff2, 0, out,
                               1536, 1536, DIM, DIM);
        } else {
            hipLaunchKernelGGL((gemm_naive<false, false, true, true>), dim3(DIM / 256, TOK / 4), dim3(256), 0, stream,
                               ffc, w_ff2 + (size_t)c * 1536 * DIM, out, nullptr, 0, out,
                               1536, 1536, DIM, DIM);
        }
    }
}

// Round 7
// 1438.577 us; speedup vs baseline: 10.1361x; 10.1361x over previous
//
#include <hip/hip_runtime.h>
#include <hip/hip_bf16.h>
#include <math.h>
#include <stdint.h>

#define BATCH 8
#define SEQ   1024
#define DIM   768
#define HEADS 12
#define DHEAD 64
#define TOK   (BATCH*SEQ)      // 8192 rows
#define INNER 768
#define FFDIM 3072
#define QKVN  2304

typedef float floatx4 __attribute__((ext_vector_type(4)));
typedef __bf16 bf16x8 __attribute__((ext_vector_type(8)));

__device__ __forceinline__ float b2f(uint16_t u) {
    return __uint_as_float(((uint32_t)u) << 16);
}
__device__ __forceinline__ uint16_t f2b(float f) {
    uint32_t x = __float_as_uint(f);
    x += 0x7fffu + ((x >> 16) & 1u);   // RNE
    return (uint16_t)(x >> 16);
}
__device__ __forceinline__ void unpack8(uint4 u, float* f) {
    f[0] = __uint_as_float((u.x & 0xffffu) << 16);
    f[1] = __uint_as_float(u.x & 0xffff0000u);
    f[2] = __uint_as_float((u.y & 0xffffu) << 16);
    f[3] = __uint_as_float(u.y & 0xffff0000u);
    f[4] = __uint_as_float((u.z & 0xffffu) << 16);
    f[5] = __uint_as_float(u.z & 0xffff0000u);
    f[6] = __uint_as_float((u.w & 0xffffu) << 16);
    f[7] = __uint_as_float(u.w & 0xffff0000u);
}

// ---- fused fp32->bf16 convert + transpose: in[R][C] fp32 -> outT[C][R] bf16 ----
__global__ __launch_bounds__(256) void transpose_convert(
    const float* __restrict__ in, uint16_t* __restrict__ outT, int R, int C)
{
    __shared__ float tile[32][33];
    int c0 = blockIdx.x * 32, r0 = blockIdx.y * 32;
    int x = threadIdx.x;   // 0..31
    int y = threadIdx.y;   // 0..7
    #pragma unroll
    for (int i = y; i < 32; i += 8)
        tile[i][x] = in[(size_t)(r0 + i) * C + c0 + x];
    __syncthreads();
    #pragma unroll
    for (int i = y; i < 32; i += 8)
        outT[(size_t)(c0 + i) * R + r0 + x] = f2b(tile[x][i]);
}

// ---- LayerNorm: one wave per row of 768, fp32 in, bf16 out (proven R6) ----
__global__ __launch_bounds__(64) void ln_naive(
    const float* __restrict__ x, const float* __restrict__ g,
    const float* __restrict__ be, uint16_t* __restrict__ y)
{
    const int lane = threadIdx.x;
    const size_t row = blockIdx.x;
    float v[12];
    float s = 0.f, ss = 0.f;
    #pragma unroll
    for (int j = 0; j < 12; j++) {
        int idx = lane + j * 64;
        float f = x[row * DIM + idx];
        v[j] = f; s += f; ss += f * f;
    }
    #pragma unroll
    for (int off = 32; off > 0; off >>= 1) {
        s  += __shfl_xor(s, off);
        ss += __shfl_xor(ss, off);
    }
    const float mu = s * (1.f / DIM);
    const float var = ss * (1.f / DIM) - mu * mu;
    const float rstd = rsqrtf(var + 1e-5f);
    #pragma unroll
    for (int j = 0; j < 12; j++) {
        int idx = lane + j * 64;
        y[row * DIM + idx] = f2b((v[j] - mu) * rstd * g[idx] + be[idx]);
    }
}

// ---- MFMA GEMM (m93 structure): C[M][N] = A[M][K](lda) @ Bt[N][K](ldbt)^T ----
// bias/res fp32. OUTF: write fp32 to C else bf16. res stride = ldc.
template<bool BIAS, bool GELU, bool RES, bool OUTF>
__global__ __launch_bounds__(256) void gemm_bt(
    const uint16_t* __restrict__ A, const uint16_t* __restrict__ Bt,
    void* C, const float* __restrict__ bias, int bias_off,
    const float* res, int N, int K, int lda, int ldbt, int ldc)
{
    __shared__ __align__(16) uint16_t a_tile[128 * 32];
    __shared__ __align__(16) uint16_t b_tile[128 * 32];
    const int tid = threadIdx.x;
    const int wave = tid >> 6, lane = tid & 63;
    const int wr = wave >> 1, wc = wave & 1;
    const int tileM = blockIdx.y * 128, tileN = blockIdx.x * 128;

    floatx4 acc[4][4] = {};

    const int scol = (tid & 3) * 8;      // 8 bf16 = 16B
    const int srow = tid >> 2;           // 0..63
    const int lm = lane & 15;
    const int lq = lane >> 4;
    const int kq = lq * 8;

    for (int k0 = 0; k0 < K; k0 += 32) {
        uint4 areg[2], breg[2];
        #pragma unroll
        for (int i = 0; i < 2; i++) {
            int row = i * 64 + srow;
            areg[i] = *(const uint4*)(A  + (size_t)(tileM + row) * lda  + k0 + scol);
            breg[i] = *(const uint4*)(Bt + (size_t)(tileN + row) * ldbt + k0 + scol);
        }
        __syncthreads();
        #pragma unroll
        for (int i = 0; i < 2; i++) {
            int row = i * 64 + srow;
            *(uint4*)&a_tile[row * 32 + scol] = areg[i];
            *(uint4*)&b_tile[row * 32 + scol] = breg[i];
        }
        __syncthreads();

        bf16x8 af[4], bfr[4];
        #pragma unroll
        for (int rt = 0; rt < 4; rt++) {
            int r = wr * 64 + rt * 16 + lm;
            af[rt] = *(const bf16x8*)&a_tile[r * 32 + kq];
        }
        #pragma unroll
        for (int nt = 0; nt < 4; nt++) {
            int n = wc * 64 + nt * 16 + lm;
            bfr[nt] = *(const bf16x8*)&b_tile[n * 32 + kq];
        }
        #pragma unroll
        for (int rt = 0; rt < 4; rt++)
            #pragma unroll
            for (int nt = 0; nt < 4; nt++)
                acc[rt][nt] = __builtin_amdgcn_mfma_f32_16x16x32_bf16(
                    af[rt], bfr[nt], acc[rt][nt], 0, 0, 0);
    }

    // epilogue: C/D layout col=lane&15, row=(lane>>4)*4+reg (m89/m91 verified)
    #pragma unroll
    for (int rt = 0; rt < 4; rt++) {
        int r0 = tileM + wr * 64 + rt * 16 + lq * 4;
        #pragma unroll
        for (int nt = 0; nt < 4; nt++) {
            int cg = tileN + wc * 64 + nt * 16 + lm;
            float bvv = BIAS ? bias[bias_off + cg] : 0.f;
            #pragma unroll
            for (int r = 0; r < 4; r++) {
                float v = acc[rt][nt][r] + bvv;
                if (GELU) v = 0.5f * v * (1.f + erff(v * 0.70710678118f));
                size_t ci = (size_t)(r0 + r) * ldc + cg;
                if (RES) v += res[ci];
                if (OUTF) ((float*)C)[ci] = v;
                else      ((uint16_t*)C)[ci] = f2b(v);
            }
        }
    }
}

// ---- flash attention over bf16 qkv[TOK][2304], O written into Q slots ----
// grid (16 qblocks, 12 heads, 8 batch), 256 threads, 64 q-rows/block, KT=32
__global__ __launch_bounds__(256) void flash_attn(uint16_t* qkv)
{
    __shared__ __align__(16) float q_s[64][68];
    __shared__ __align__(16) float k_s[32][68];
    __shared__ __align__(16) float v_s[32][68];
    __shared__ float s_s[64][33];
    __shared__ float m_s[64], l_s[64], a_s[64];

    const int t = threadIdx.x;
    const int qb = blockIdx.x, h = blockIdx.y, b = blockIdx.z;
    const size_t rowbase = (size_t)b * SEQ;
    const int qr = t >> 2, d0 = (t & 3) * 16;

    {   // load+scale Q block (reads own future output slots BEFORE any write)
        const uint16_t* src = qkv + (rowbase + qb * 64 + qr) * QKVN + h * DHEAD + d0;
        #pragma unroll
        for (int j = 0; j < 2; j++) {
            uint4 u = *(const uint4*)(src + j * 8);
            float f[8]; unpack8(u, f);
            #pragma unroll
            for (int i = 0; i < 8; i++) q_s[qr][d0 + j * 8 + i] = f[i] * 0.125f;
        }
    }
    if (t < 64) { m_s[t] = -1e30f; l_s[t] = 0.f; }
    float O[16];
    #pragma unroll
    for (int i = 0; i < 16; i++) O[i] = 0.f;
    __syncthreads();

    for (int kt = 0; kt < SEQ / 32; ++kt) {
        {   // stage K,V tile (cols 768..2303 — never written by anyone)
            const int row = t >> 3, dd = (t & 7) * 8;
            const uint16_t* kp = qkv + (rowbase + kt * 32 + row) * QKVN + INNER + h * DHEAD + dd;
            uint4 u = *(const uint4*)kp;
            float f[8]; unpack8(u, f);
            #pragma unroll
            for (int i = 0; i < 8; i++) k_s[row][dd + i] = f[i];
            uint4 w = *(const uint4*)(kp + INNER);
            unpack8(w, f);
            #pragma unroll
            for (int i = 0; i < 8; i++) v_s[row][dd + i] = f[i];
        }
        __syncthreads();

        {   // scores: 2 q-rows x 4 k-cols per thread
            const int q0 = (t >> 3) * 2, k0 = (t & 7) * 4;
            float sacc[2][4] = {};
            #pragma unroll 4
            for (int d = 0; d < 64; d += 4) {
                float4 qa0 = *(const float4*)&q_s[q0][d];
                float4 qa1 = *(const float4*)&q_s[q0 + 1][d];
                #pragma unroll
                for (int j = 0; j < 4; j++) {
                    float4 kb = *(const float4*)&k_s[k0 + j][d];
                    sacc[0][j] += qa0.x * kb.x + qa0.y * kb.y + qa0.z * kb.z + qa0.w * kb.w;
                    sacc[1][j] += qa1.x * kb.x + qa1.y * kb.y + qa1.z * kb.z + qa1.w * kb.w;
                }
            }
            #pragma unroll
            for (int i = 0; i < 2; i++)
                #pragma unroll
                for (int j = 0; j < 4; j++)
                    s_s[q0 + i][k0 + j] = sacc[i][j];
        }
        __syncthreads();

        if (t < 64) {   // online softmax row update
            float mo = m_s[t], mn = mo;
            #pragma unroll
            for (int k = 0; k < 32; k++) mn = fmaxf(mn, s_s[t][k]);
            float al = __expf(mo - mn);
            float sum = 0.f;
            #pragma unroll
            for (int k = 0; k < 32; k++) {
                float p = __expf(s_s[t][k] - mn);
                s_s[t][k] = p; sum += p;
            }
            l_s[t] = l_s[t] * al + sum;
            m_s[t] = mn; a_s[t] = al;
        }
        __syncthreads();

        {   // O = O*alpha + P @ V_tile ; thread owns (qr, 16 d's)
            float al = a_s[qr];
            #pragma unroll
            for (int i = 0; i < 16; i++) O[i] *= al;
            #pragma unroll 4
            for (int kk = 0; kk < 32; ++kk) {
                float p = s_s[qr][kk];
                const float* vr = &v_s[kk][d0];
                float4 v0 = *(const float4*)(vr);
                float4 v1 = *(const float4*)(vr + 4);
                float4 v2 = *(const float4*)(vr + 8);
                float4 v3 = *(const float4*)(vr + 12);
                O[0]  += p * v0.x; O[1]  += p * v0.y; O[2]  += p * v0.z; O[3]  += p * v0.w;
                O[4]  += p * v1.x; O[5]  += p * v1.y; O[6]  += p * v1.z; O[7]  += p * v1.w;
                O[8]  += p * v2.x; O[9]  += p * v2.y; O[10] += p * v2.z; O[11] += p * v2.w;
                O[12] += p * v3.x; O[13] += p * v3.y; O[14] += p * v3.z; O[15] += p * v3.w;
            }
        }
        __syncthreads();
    }

    float inv = 1.f / l_s[qr];
    uint16_t* dst = qkv + (rowbase + qb * 64 + qr) * QKVN + h * DHEAD + d0;
    #pragma unroll
    for (int i = 0; i < 16; i++) dst[i] = f2b(O[i] * inv);
}

extern "C" void kernel_launch(void* const* d_in, const int* in_sizes, int n_in,
                              void* d_out, int out_size, void* d_ws, size_t ws_size,
                              hipStream_t stream) {
    const float* x      = (const float*)d_in[0];   // [8192][768] fp32
    const float* ln1_g  = (const float*)d_in[1];
    const float* ln1_b  = (const float*)d_in[2];
    const float* ln2_g  = (const float*)d_in[3];
    const float* ln2_b  = (const float*)d_in[4];
    const float* w_qkv  = (const float*)d_in[5];   // [768][2304]
    const float* w_out  = (const float*)d_in[6];   // [768][768]
    const float* b_out  = (const float*)d_in[7];
    const float* w_ff1  = (const float*)d_in[8];   // [768][3072]
    const float* b_ff1  = (const float*)d_in[9];
    const float* w_ff2  = (const float*)d_in[10];  // [3072][768]
    const float* b_ff2  = (const float*)d_in[11];
    float* out = (float*)d_out;                    // [8192][768] fp32

    // ws layout (uint16 elements), peak 64.5 MB (proven safe R3/R4)
    uint16_t* ws  = (uint16_t*)d_ws;
    uint16_t* qkv = ws;                            // [8192][2304]
    uint16_t* ffc = ws;                            // [8192][1536] (reuses dead qkv)
    uint16_t* h   = ws + (size_t)18874368;         // [8192][768]
    uint16_t* WqT = ws + (size_t)25165824;         // [2304][768]
    uint16_t* WoT = ws + (size_t)26935296;         // [768][768]
    uint16_t* W1T = ws + (size_t)27525120;         // [3072][768]
    uint16_t* W2T = ws + (size_t)29884416;         // [768][3072]

    dim3 tb(32, 8);
    hipLaunchKernelGGL(transpose_convert, dim3(QKVN/32, DIM/32), tb, 0, stream, w_qkv, WqT, DIM, QKVN);
    hipLaunchKernelGGL(transpose_convert, dim3(DIM/32,  DIM/32), tb, 0, stream, w_out, WoT, DIM, DIM);
    hipLaunchKernelGGL(transpose_convert, dim3(FFDIM/32, DIM/32), tb, 0, stream, w_ff1, W1T, DIM, FFDIM);
    hipLaunchKernelGGL(transpose_convert, dim3(DIM/32, FFDIM/32), tb, 0, stream, w_ff2, W2T, FFDIM, DIM);

    // h = LN1(x)
    hipLaunchKernelGGL(ln_naive, dim3(TOK), dim3(64), 0, stream, x, ln1_g, ln1_b, h);
    // qkv = h @ w_qkv  (bf16 out)
    hipLaunchKernelGGL((gemm_bt<false, false, false, false>), dim3(QKVN/128, TOK/128), dim3(256), 0, stream,
                       h, WqT, qkv, nullptr, 0, nullptr, QKVN, DIM, DIM, DIM, QKVN);
    // attention in-place (O -> Q slots)
    hipLaunchKernelGGL(flash_attn, dim3(SEQ/64, HEADS, BATCH), dim3(256), 0, stream, qkv);
    // d_out(fp32) = x + attnO @ w_out + b_out   (A = qkv Q-slots, lda=2304)
    hipLaunchKernelGGL((gemm_bt<true, false, true, true>), dim3(DIM/128, TOK/128), dim3(256), 0, stream,
                       qkv, WoT, out, b_out, 0, x, DIM, INNER, QKVN, DIM, DIM);
    // h = LN2(d_out fp32)
    hipLaunchKernelGGL(ln_naive, dim3(TOK), dim3(64), 0, stream, out, ln2_g, ln2_b, h);
    // FFN in two hidden chunks of 1536 (ffc reuses dead qkv region)
    for (int c = 0; c < 2; c++) {
        // ffc = gelu(h @ w_ff1[:, c*1536:+1536] + b_ff1[c*1536:])  (bf16 out)
        hipLaunchKernelGGL((gemm_bt<true, true, false, false>), dim3(1536/128, TOK/128), dim3(256), 0, stream,
                           h, W1T + (size_t)c*1536*DIM, ffc, b_ff1, c*1536, nullptr,
                           1536, DIM, DIM, DIM, 1536);
        // d_out += ffc @ w_ff2[c*1536:+1536, :] (+ b_ff2 on first chunk), fp32 in-place
        if (c == 0) {
            hipLaunchKernelGGL((gemm_bt<true, false, true, true>), dim3(DIM/128, TOK/128), dim3(256), 0, stream,
                               ffc, W2T + (size_t)c*1536, out, b_ff2, 0, out,
                               DIM, 1536, 1536, FFDIM, DIM);
        } else {
            hipLaunchKernelGGL((gemm_bt<false, false, true, true>), dim3(DIM/128, TOK/128), dim3(256), 0, stream,
                               ffc, W2T + (size_t)c*1536, out, nullptr, 0, out,
                               DIM, 1536, 1536, FFDIM, DIM);
        }
    }
}

// Round 8
// 509.023 us; speedup vs baseline: 28.6462x; 2.8262x over previous
//
#include <hip/hip_runtime.h>
#include <hip/hip_bf16.h>
#include <math.h>
#include <stdint.h>

#define BATCH 8
#define SEQ   1024
#define DIM   768
#define HEADS 12
#define DHEAD 64
#define TOK   (BATCH*SEQ)      // 8192 rows
#define INNER 768
#define FFDIM 3072
#define QKVN  2304

typedef float floatx4 __attribute__((ext_vector_type(4)));
typedef __bf16 bf16x8 __attribute__((ext_vector_type(8)));

__device__ __forceinline__ float b2f(uint16_t u) {
    return __uint_as_float(((uint32_t)u) << 16);
}
__device__ __forceinline__ uint16_t f2b(float f) {
    uint32_t x = __float_as_uint(f);
    x += 0x7fffu + ((x >> 16) & 1u);   // RNE
    return (uint16_t)(x >> 16);
}

// async global->LDS, 16B per lane (m97 pattern; LDS dest must be base+lane*16)
__device__ __forceinline__ void gload_lds16(const uint16_t* g, uint16_t* l) {
    __builtin_amdgcn_global_load_lds(
        (const __attribute__((address_space(1))) uint32_t*)g,
        (__attribute__((address_space(3))) uint32_t*)l, 16, 0, 0);
}

// ---- fused fp32->bf16 convert + transpose: in[R][C] fp32 -> outT[C][R] bf16 ----
__global__ __launch_bounds__(256) void transpose_convert(
    const float* __restrict__ in, uint16_t* __restrict__ outT, int R, int C)
{
    __shared__ float tile[32][33];
    int c0 = blockIdx.x * 32, r0 = blockIdx.y * 32;
    int x = threadIdx.x;   // 0..31
    int y = threadIdx.y;   // 0..7
    #pragma unroll
    for (int i = y; i < 32; i += 8)
        tile[i][x] = in[(size_t)(r0 + i) * C + c0 + x];
    __syncthreads();
    #pragma unroll
    for (int i = y; i < 32; i += 8)
        outT[(size_t)(c0 + i) * R + r0 + x] = f2b(tile[x][i]);
}

// ---- LayerNorm: one wave per row of 768, fp32 in, bf16 out ----
__global__ __launch_bounds__(64) void ln_naive(
    const float* __restrict__ x, const float* __restrict__ g,
    const float* __restrict__ be, uint16_t* __restrict__ y)
{
    const int lane = threadIdx.x;
    const size_t row = blockIdx.x;
    float v[12];
    float s = 0.f, ss = 0.f;
    #pragma unroll
    for (int j = 0; j < 12; j++) {
        int idx = lane + j * 64;
        float f = x[row * DIM + idx];
        v[j] = f; s += f; ss += f * f;
    }
    #pragma unroll
    for (int off = 32; off > 0; off >>= 1) {
        s  += __shfl_xor(s, off);
        ss += __shfl_xor(ss, off);
    }
    const float mu = s * (1.f / DIM);
    const float var = ss * (1.f / DIM) - mu * mu;
    const float rstd = rsqrtf(var + 1e-5f);
    #pragma unroll
    for (int j = 0; j < 12; j++) {
        int idx = lane + j * 64;
        y[row * DIM + idx] = f2b((v[j] - mu) * rstd * g[idx] + be[idx]);
    }
}

// ---- MFMA GEMM (m97 structure, global_load_lds width-16 staging) ----
// C[M][N] = A[M][K](lda) @ Bt[N][K](ldbt)^T ; bias/res fp32; OUTF: fp32 out.
template<bool BIAS, bool GELU, bool RES, bool OUTF>
__global__ __launch_bounds__(256) void gemm_bt(
    const uint16_t* __restrict__ A, const uint16_t* __restrict__ Bt,
    void* C, const float* __restrict__ bias, int bias_off,
    const float* res, int N, int K, int lda, int ldbt, int ldc)
{
    __shared__ __align__(16) uint16_t a_tile[128 * 32];
    __shared__ __align__(16) uint16_t b_tile[128 * 32];
    const int tid = threadIdx.x;
    const int wave = tid >> 6, lane = tid & 63;
    const int wr = wave >> 1, wc = wave & 1;
    const int tileM = blockIdx.y * 128, tileN = blockIdx.x * 128;

    floatx4 acc[4][4] = {};

    const int scol = (tid & 3) * 8;      // 8 bf16 = 16B  (byte off = tid*16: DMA-compatible)
    const int srow = tid >> 2;           // 0..63
    const int lm = lane & 15;
    const int lq = lane >> 4;
    const int kq = lq * 8;

    for (int k0 = 0; k0 < K; k0 += 32) {
        __syncthreads();   // prior iteration's ds_reads complete before overwrite
        #pragma unroll
        for (int i = 0; i < 2; i++) {
            int row = i * 64 + srow;
            gload_lds16(A  + (size_t)(tileM + row) * lda  + k0 + scol, &a_tile[row * 32 + scol]);
            gload_lds16(Bt + (size_t)(tileN + row) * ldbt + k0 + scol, &b_tile[row * 32 + scol]);
        }
        __syncthreads();   // drains vmcnt -> staged data visible

        bf16x8 af[4], bfr[4];
        #pragma unroll
        for (int rt = 0; rt < 4; rt++) {
            int r = wr * 64 + rt * 16 + lm;
            af[rt] = *(const bf16x8*)&a_tile[r * 32 + kq];
        }
        #pragma unroll
        for (int nt = 0; nt < 4; nt++) {
            int n = wc * 64 + nt * 16 + lm;
            bfr[nt] = *(const bf16x8*)&b_tile[n * 32 + kq];
        }
        #pragma unroll
        for (int rt = 0; rt < 4; rt++)
            #pragma unroll
            for (int nt = 0; nt < 4; nt++)
                acc[rt][nt] = __builtin_amdgcn_mfma_f32_16x16x32_bf16(
                    af[rt], bfr[nt], acc[rt][nt], 0, 0, 0);
    }

    // epilogue: C/D layout col=lane&15, row=(lane>>4)*4+reg (m89/m91 verified)
    #pragma unroll
    for (int rt = 0; rt < 4; rt++) {
        int r0 = tileM + wr * 64 + rt * 16 + lq * 4;
        #pragma unroll
        for (int nt = 0; nt < 4; nt++) {
            int cg = tileN + wc * 64 + nt * 16 + lm;
            float bvv = BIAS ? bias[bias_off + cg] : 0.f;
            #pragma unroll
            for (int r = 0; r < 4; r++) {
                float v = acc[rt][nt][r] + bvv;
                if (GELU) v = 0.5f * v * (1.f + erff(v * 0.70710678118f));
                size_t ci = (size_t)(r0 + r) * ldc + cg;
                if (RES) v += res[ci];
                if (OUTF) ((float*)C)[ci] = v;
                else      ((uint16_t*)C)[ci] = f2b(v);
            }
        }
    }
}

// ---- MFMA flash attention: qkv[TOK][2304] bf16, O written into Q slots ----
// grid (16,12,8); 256 thr = 4 waves; wave wq owns q-rows [wq*16, wq*16+16); KT=64.
#define KSTR 72
#define VSTR 72
#define PSTR 72
__global__ __launch_bounds__(256) void flash_mfma(uint16_t* qkv)
{
    __shared__ __align__(16) uint16_t k_s [64 * KSTR];
    __shared__ __align__(16) uint16_t vt_s[64 * VSTR];
    __shared__ __align__(16) uint16_t p_s [64 * PSTR];

    const int t = threadIdx.x;
    const int wq = t >> 6;
    const int lane = t & 63;
    const int lm = lane & 15;
    const int lq = lane >> 4;            // 0..3

    const int qb = blockIdx.x, h = blockIdx.y, b = blockIdx.z;
    const size_t rowbase = (size_t)b * SEQ;
    const int hcol = h * DHEAD;

    // Q A-fragments, loaded once direct from global (before any in-place write)
    bf16x8 af_q[2];
    {
        const uint16_t* qp = qkv + (rowbase + qb*64 + wq*16 + lm) * QKVN + hcol + lq*8;
        af_q[0] = *(const bf16x8*)qp;
        af_q[1] = *(const bf16x8*)(qp + 32);
    }

    floatx4 O[4] = {};
    float mrow[4] = {-1e30f, -1e30f, -1e30f, -1e30f};
    float lrow[4] = {0.f, 0.f, 0.f, 0.f};

    const int s_row = t >> 2;            // 0..63 (kpos within tile)
    const int s_dc  = (t & 3) * 16;      // d-chunk base

    for (int kt = 0; kt < SEQ / 64; ++kt) {
        {   // stage K tile (vector) + V^T tile (xor-swizzled scalar scatter)
            const uint16_t* kp = qkv + (rowbase + kt*64 + s_row) * QKVN + INNER + hcol + s_dc;
            uint4 u0 = *(const uint4*)kp;
            uint4 u1 = *(const uint4*)(kp + 8);
            *(uint4*)&k_s[s_row * KSTR + s_dc]     = u0;
            *(uint4*)&k_s[s_row * KSTR + s_dc + 8] = u1;
            const uint16_t* vp = kp + INNER;
            uint4 w0 = *(const uint4*)vp;
            uint4 w1 = *(const uint4*)(vp + 8);
            const uint32_t wv[8] = {w0.x, w0.y, w0.z, w0.w, w1.x, w1.y, w1.z, w1.w};
            #pragma unroll
            for (int j = 0; j < 16; j++) {
                int d = s_dc + j;
                uint16_t val = (j & 1) ? (uint16_t)(wv[j >> 1] >> 16)
                                       : (uint16_t)(wv[j >> 1] & 0xffffu);
                vt_s[d * VSTR + (s_row ^ (((d >> 3) & 7) << 3))] = val;
            }
        }
        __syncthreads();

        // S = Q K^T : 16q x 64kpos per wave, contraction over d (both natural)
        floatx4 S[4];
        #pragma unroll
        for (int nt = 0; nt < 4; nt++) {
            bf16x8 bk0 = *(const bf16x8*)&k_s[(nt*16 + lm) * KSTR + lq*8];
            bf16x8 bk1 = *(const bf16x8*)&k_s[(nt*16 + lm) * KSTR + 32 + lq*8];
            floatx4 a = {};
            a = __builtin_amdgcn_mfma_f32_16x16x32_bf16(af_q[0], bk0, a, 0, 0, 0);
            a = __builtin_amdgcn_mfma_f32_16x16x32_bf16(af_q[1], bk1, a, 0, 0, 0);
            S[nt] = a;
        }

        // online softmax; lane holds q-rows lq*4+r, kpos nt*16+lm
        float p[4][4], alpha[4];
        #pragma unroll
        for (int r = 0; r < 4; r++) {
            float mx = fmaxf(fmaxf(S[0][r], S[1][r]), fmaxf(S[2][r], S[3][r])) * 0.125f;
            #pragma unroll
            for (int off = 8; off >= 1; off >>= 1)
                mx = fmaxf(mx, __shfl_xor(mx, off));
            float mn = fmaxf(mrow[r], mx);
            alpha[r] = __expf(mrow[r] - mn);
            mrow[r] = mn;
            float sum = 0.f;
            #pragma unroll
            for (int nt = 0; nt < 4; nt++) {
                float pv = __expf(S[nt][r] * 0.125f - mn);
                p[nt][r] = pv; sum += pv;
            }
            #pragma unroll
            for (int off = 8; off >= 1; off >>= 1)
                sum += __shfl_xor(sum, off);
            lrow[r] = lrow[r] * alpha[r] + sum;
        }

        // P -> LDS (A-layout round trip; wave-local rows)
        #pragma unroll
        for (int nt = 0; nt < 4; nt++)
            #pragma unroll
            for (int r = 0; r < 4; r++)
                p_s[(wq*16 + lq*4 + r) * PSTR + nt*16 + lm] = f2b(p[nt][r]);

        // O rescale
        #pragma unroll
        for (int nt = 0; nt < 4; nt++)
            #pragma unroll
            for (int r = 0; r < 4; r++)
                O[nt][r] *= alpha[r];

        // PV: A = P[q][kpos], B = V^T[d][kpos] (swizzled)
        #pragma unroll
        for (int ks = 0; ks < 2; ks++) {
            bf16x8 ap = *(const bf16x8*)&p_s[(wq*16 + lm) * PSTR + ks*32 + lq*8];
            #pragma unroll
            for (int nt = 0; nt < 4; nt++) {
                int d = nt*16 + lm;
                bf16x8 bv = *(const bf16x8*)&vt_s[d * VSTR + ((ks*32 + lq*8) ^ (((d >> 3) & 7) << 3))];
                O[nt] = __builtin_amdgcn_mfma_f32_16x16x32_bf16(ap, bv, O[nt], 0, 0, 0);
            }
        }
        __syncthreads();   // protect k_s/vt_s before next staging
    }

    // write O/l into this block's Q slots
    #pragma unroll
    for (int r = 0; r < 4; r++) {
        float inv = 1.f / lrow[r];
        uint16_t* dst = qkv + (rowbase + qb*64 + wq*16 + lq*4 + r) * QKVN + hcol;
        #pragma unroll
        for (int nt = 0; nt < 4; nt++)
            dst[nt*16 + lm] = f2b(O[nt][r] * inv);
    }
}

extern "C" void kernel_launch(void* const* d_in, const int* in_sizes, int n_in,
                              void* d_out, int out_size, void* d_ws, size_t ws_size,
                              hipStream_t stream) {
    const float* x      = (const float*)d_in[0];   // [8192][768] fp32
    const float* ln1_g  = (const float*)d_in[1];
    const float* ln1_b  = (const float*)d_in[2];
    const float* ln2_g  = (const float*)d_in[3];
    const float* ln2_b  = (const float*)d_in[4];
    const float* w_qkv  = (const float*)d_in[5];   // [768][2304]
    const float* w_out  = (const float*)d_in[6];   // [768][768]
    const float* b_out  = (const float*)d_in[7];
    const float* w_ff1  = (const float*)d_in[8];   // [768][3072]
    const float* b_ff1  = (const float*)d_in[9];
    const float* w_ff2  = (const float*)d_in[10];  // [3072][768]
    const float* b_ff2  = (const float*)d_in[11];
    float* out = (float*)d_out;                    // [8192][768] fp32

    // ws layout (uint16 elements), peak 64.5 MB (proven safe)
    uint16_t* ws  = (uint16_t*)d_ws;
    uint16_t* qkv = ws;                            // [8192][2304]
    uint16_t* ffc = ws;                            // [8192][1536] (reuses dead qkv)
    uint16_t* h   = ws + (size_t)18874368;         // [8192][768]
    uint16_t* WqT = ws + (size_t)25165824;         // [2304][768]
    uint16_t* WoT = ws + (size_t)26935296;         // [768][768]
    uint16_t* W1T = ws + (size_t)27525120;         // [3072][768]
    uint16_t* W2T = ws + (size_t)29884416;         // [768][3072]

    dim3 tb(32, 8);
    hipLaunchKernelGGL(transpose_convert, dim3(QKVN/32, DIM/32), tb, 0, stream, w_qkv, WqT, DIM, QKVN);
    hipLaunchKernelGGL(transpose_convert, dim3(DIM/32,  DIM/32), tb, 0, stream, w_out, WoT, DIM, DIM);
    hipLaunchKernelGGL(transpose_convert, dim3(FFDIM/32, DIM/32), tb, 0, stream, w_ff1, W1T, DIM, FFDIM);
    hipLaunchKernelGGL(transpose_convert, dim3(DIM/32, FFDIM/32), tb, 0, stream, w_ff2, W2T, FFDIM, DIM);

    // h = LN1(x)
    hipLaunchKernelGGL(ln_naive, dim3(TOK), dim3(64), 0, stream, x, ln1_g, ln1_b, h);
    // qkv = h @ w_qkv
    hipLaunchKernelGGL((gemm_bt<false, false, false, false>), dim3(QKVN/128, TOK/128), dim3(256), 0, stream,
                       h, WqT, qkv, nullptr, 0, nullptr, QKVN, DIM, DIM, DIM, QKVN);
    // attention in-place (O -> Q slots)
    hipLaunchKernelGGL(flash_mfma, dim3(SEQ/64, HEADS, BATCH), dim3(256), 0, stream, qkv);
    // d_out(fp32) = x + attnO @ w_out + b_out
    hipLaunchKernelGGL((gemm_bt<true, false, true, true>), dim3(DIM/128, TOK/128), dim3(256), 0, stream,
                       qkv, WoT, out, b_out, 0, x, DIM, INNER, QKVN, DIM, DIM);
    // h = LN2(d_out)
    hipLaunchKernelGGL(ln_naive, dim3(TOK), dim3(64), 0, stream, out, ln2_g, ln2_b, h);
    // FFN in two hidden chunks of 1536 (ffc reuses dead qkv region)
    for (int c = 0; c < 2; c++) {
        hipLaunchKernelGGL((gemm_bt<true, true, false, false>), dim3(1536/128, TOK/128), dim3(256), 0, stream,
                           h, W1T + (size_t)c*1536*DIM, ffc, b_ff1, c*1536, nullptr,
                           1536, DIM, DIM, DIM, 1536);
        if (c == 0) {
            hipLaunchKernelGGL((gemm_bt<true, false, true, true>), dim3(DIM/128, TOK/128), dim3(256), 0, stream,
                               ffc, W2T + (size_t)c*1536, out, b_ff2, 0, out,
                               DIM, 1536, 1536, FFDIM, DIM);
        } else {
            hipLaunchKernelGGL((gemm_bt<false, false, true, true>), dim3(DIM/128, TOK/128), dim3(256), 0, stream,
                               ffc, W2T + (size_t)c*1536, out, nullptr, 0, out,
                               DIM, 1536, 1536, FFDIM, DIM);
        }
    }
}

// Round 9
// 503.536 us; speedup vs baseline: 28.9584x; 1.0109x over previous
//
#include <hip/hip_runtime.h>
#include <hip/hip_bf16.h>
#include <math.h>
#include <stdint.h>

#define BATCH 8
#define SEQ   1024
#define DIM   768
#define HEADS 12
#define DHEAD 64
#define TOK   (BATCH*SEQ)      // 8192 rows
#define INNER 768
#define FFDIM 3072
#define QKVN  2304
#define QKLD  1536             // qk buffer row stride (Q,K only; V split out)

typedef float floatx4 __attribute__((ext_vector_type(4)));
typedef __bf16 bf16x8 __attribute__((ext_vector_type(8)));

__device__ __forceinline__ float b2f(uint16_t u) {
    return __uint_as_float(((uint32_t)u) << 16);
}
__device__ __forceinline__ uint16_t f2b(float f) {
    uint32_t x = __float_as_uint(f);
    x += 0x7fffu + ((x >> 16) & 1u);   // RNE
    return (uint16_t)(x >> 16);
}

// async global->LDS, 16B per lane (m97 pattern; LDS dest = base + lane*16)
__device__ __forceinline__ void gload_lds16(const uint16_t* g, uint16_t* l) {
    __builtin_amdgcn_global_load_lds(
        (const __attribute__((address_space(1))) uint32_t*)g,
        (__attribute__((address_space(3))) uint32_t*)l, 16, 0, 0);
}

// ---- fused fp32->bf16 convert + transpose: in[R][C] fp32 -> outT[C][R] bf16 ----
__global__ __launch_bounds__(256) void transpose_convert(
    const float* __restrict__ in, uint16_t* __restrict__ outT, int R, int C)
{
    __shared__ float tile[32][33];
    int c0 = blockIdx.x * 32, r0 = blockIdx.y * 32;
    int x = threadIdx.x;   // 0..31
    int y = threadIdx.y;   // 0..7
    #pragma unroll
    for (int i = y; i < 32; i += 8)
        tile[i][x] = in[(size_t)(r0 + i) * C + c0 + x];
    __syncthreads();
    #pragma unroll
    for (int i = y; i < 32; i += 8)
        outT[(size_t)(c0 + i) * R + r0 + x] = f2b(tile[x][i]);
}

// ---- LayerNorm: one wave per row of 768, fp32 in, bf16 out ----
__global__ __launch_bounds__(64) void ln_naive(
    const float* __restrict__ x, const float* __restrict__ g,
    const float* __restrict__ be, uint16_t* __restrict__ y)
{
    const int lane = threadIdx.x;
    const size_t row = blockIdx.x;
    float v[12];
    float s = 0.f, ss = 0.f;
    #pragma unroll
    for (int j = 0; j < 12; j++) {
        int idx = lane + j * 64;
        float f = x[row * DIM + idx];
        v[j] = f; s += f; ss += f * f;
    }
    #pragma unroll
    for (int off = 32; off > 0; off >>= 1) {
        s  += __shfl_xor(s, off);
        ss += __shfl_xor(ss, off);
    }
    const float mu = s * (1.f / DIM);
    const float var = ss * (1.f / DIM) - mu * mu;
    const float rstd = rsqrtf(var + 1e-5f);
    #pragma unroll
    for (int j = 0; j < 12; j++) {
        int idx = lane + j * 64;
        y[row * DIM + idx] = f2b((v[j] - mu) * rstd * g[idx] + be[idx]);
    }
}

// ---- MFMA GEMM (m97 structure): C[M][N] = A[M][K](lda) @ Bt[N][K](ldbt)^T ----
// VSPLIT: tiles with tileN>=1536 write transposed to vt[b][d][s] (QKV launch).
template<bool BIAS, bool GELU, bool RES, bool OUTF, bool VSPLIT>
__global__ __launch_bounds__(256) void gemm_bt(
    const uint16_t* __restrict__ A, const uint16_t* __restrict__ Bt,
    void* C, const float* __restrict__ bias, int bias_off,
    const float* res, int N, int K, int lda, int ldbt, int ldc,
    uint16_t* __restrict__ vt)
{
    __shared__ __align__(16) uint16_t a_tile[128 * 32];
    __shared__ __align__(16) uint16_t b_tile[128 * 32];
    const int tid = threadIdx.x;
    const int wave = tid >> 6, lane = tid & 63;
    const int wr = wave >> 1, wc = wave & 1;
    const int tileM = blockIdx.y * 128, tileN = blockIdx.x * 128;

    floatx4 acc[4][4] = {};

    const int scol = (tid & 3) * 8;      // byte off = tid*16 (DMA-compatible)
    const int srow = tid >> 2;           // 0..63
    const int lm = lane & 15;
    const int lq = lane >> 4;
    const int kq = lq * 8;

    for (int k0 = 0; k0 < K; k0 += 32) {
        __syncthreads();
        #pragma unroll
        for (int i = 0; i < 2; i++) {
            int row = i * 64 + srow;
            gload_lds16(A  + (size_t)(tileM + row) * lda  + k0 + scol, &a_tile[row * 32 + scol]);
            gload_lds16(Bt + (size_t)(tileN + row) * ldbt + k0 + scol, &b_tile[row * 32 + scol]);
        }
        __syncthreads();

        bf16x8 af[4], bfr[4];
        #pragma unroll
        for (int rt = 0; rt < 4; rt++) {
            int r = wr * 64 + rt * 16 + lm;
            af[rt] = *(const bf16x8*)&a_tile[r * 32 + kq];
        }
        #pragma unroll
        for (int nt = 0; nt < 4; nt++) {
            int n = wc * 64 + nt * 16 + lm;
            bfr[nt] = *(const bf16x8*)&b_tile[n * 32 + kq];
        }
        #pragma unroll
        for (int rt = 0; rt < 4; rt++)
            #pragma unroll
            for (int nt = 0; nt < 4; nt++)
                acc[rt][nt] = __builtin_amdgcn_mfma_f32_16x16x32_bf16(
                    af[rt], bfr[nt], acc[rt][nt], 0, 0, 0);
    }

    // epilogue: C/D layout col=lane&15, row=(lane>>4)*4+reg (m89/m91 verified)
    const bool vpath = VSPLIT && (tileN >= 1536);
    #pragma unroll
    for (int rt = 0; rt < 4; rt++) {
        int r0 = tileM + wr * 64 + rt * 16 + lq * 4;
        #pragma unroll
        for (int nt = 0; nt < 4; nt++) {
            int cg = tileN + wc * 64 + nt * 16 + lm;
            if (vpath) {
                // V columns -> vT[b][d][s], 4 consecutive s packed into 8B
                int d = cg - 1536;
                int bb = r0 >> 10, s0 = r0 & 1023;
                uint32_t p0 = (uint32_t)f2b(acc[rt][nt][0]) | ((uint32_t)f2b(acc[rt][nt][1]) << 16);
                uint32_t p1 = (uint32_t)f2b(acc[rt][nt][2]) | ((uint32_t)f2b(acc[rt][nt][3]) << 16);
                uint2 pk; pk.x = p0; pk.y = p1;
                *(uint2*)&vt[((size_t)bb * 768 + d) * 1024 + s0] = pk;
            } else {
                float bvv = BIAS ? bias[bias_off + cg] : 0.f;
                #pragma unroll
                for (int r = 0; r < 4; r++) {
                    float v = acc[rt][nt][r] + bvv;
                    if (GELU) v = 0.5f * v * (1.f + erff(v * 0.70710678118f));
                    size_t ci = (size_t)(r0 + r) * ldc + cg;
                    if (RES) v += res[ci];
                    if (OUTF) ((float*)C)[ci] = v;
                    else      ((uint16_t*)C)[ci] = f2b(v);
                }
            }
        }
    }
}

// ---- MFMA flash attention: qk[TOK][1536] (Q,K) + vT[b][768][1024] ----
// grid (16,12,8); 256 thr = 4 waves; wave wq owns q-rows [wq*16,+16); KT=64.
// O written in-place into Q slots of qk.
#define KSTR 72
#define VSTR 72
#define PSTR 72
__global__ __launch_bounds__(256) void flash_mfma(
    uint16_t* qk, const uint16_t* __restrict__ vt)
{
    __shared__ __align__(16) uint16_t k_s [64 * KSTR];
    __shared__ __align__(16) uint16_t vt_s[64 * VSTR];
    __shared__ __align__(16) uint16_t p_s [64 * PSTR];

    const int t = threadIdx.x;
    const int wq = t >> 6;
    const int lane = t & 63;
    const int lm = lane & 15;
    const int lq = lane >> 4;            // 0..3

    const int qb = blockIdx.x, h = blockIdx.y, b = blockIdx.z;
    const size_t rowbase = (size_t)b * SEQ;
    const int hcol = h * DHEAD;

    // Q A-fragments, loaded once (before any in-place write)
    bf16x8 af_q[2];
    {
        const uint16_t* qp = qk + (rowbase + qb*64 + wq*16 + lm) * QKLD + hcol + lq*8;
        af_q[0] = *(const bf16x8*)qp;
        af_q[1] = *(const bf16x8*)(qp + 32);
    }

    floatx4 O[4] = {};
    float mrow[4] = {-1e30f, -1e30f, -1e30f, -1e30f};
    float lrow[4] = {0.f, 0.f, 0.f, 0.f};

    const int s_row = t >> 2;            // 0..63
    const int s_dc  = (t & 3) * 16;      // 0,16,32,48

    for (int kt = 0; kt < SEQ / 64; ++kt) {
        {   // stage K tile and V^T tile, both pure b128 vector moves
            const uint16_t* kp = qk + (rowbase + kt*64 + s_row) * QKLD + INNER + hcol + s_dc;
            *(uint4*)&k_s[s_row * KSTR + s_dc]     = *(const uint4*)kp;
            *(uint4*)&k_s[s_row * KSTR + s_dc + 8] = *(const uint4*)(kp + 8);
            const uint16_t* vp = vt + ((size_t)b * 768 + hcol + s_row) * 1024 + kt*64 + s_dc;
            *(uint4*)&vt_s[s_row * VSTR + s_dc]     = *(const uint4*)vp;
            *(uint4*)&vt_s[s_row * VSTR + s_dc + 8] = *(const uint4*)(vp + 8);
        }
        __syncthreads();

        // S = Q K^T : 16q x 64kpos per wave, contraction over d
        floatx4 S[4];
        #pragma unroll
        for (int nt = 0; nt < 4; nt++) {
            bf16x8 bk0 = *(const bf16x8*)&k_s[(nt*16 + lm) * KSTR + lq*8];
            bf16x8 bk1 = *(const bf16x8*)&k_s[(nt*16 + lm) * KSTR + 32 + lq*8];
            floatx4 a = {};
            a = __builtin_amdgcn_mfma_f32_16x16x32_bf16(af_q[0], bk0, a, 0, 0, 0);
            a = __builtin_amdgcn_mfma_f32_16x16x32_bf16(af_q[1], bk1, a, 0, 0, 0);
            S[nt] = a;
        }

        // online softmax; lane holds q-rows lq*4+r, kpos nt*16+lm
        float p[4][4], alpha[4];
        #pragma unroll
        for (int r = 0; r < 4; r++) {
            float mx = fmaxf(fmaxf(S[0][r], S[1][r]), fmaxf(S[2][r], S[3][r])) * 0.125f;
            #pragma unroll
            for (int off = 8; off >= 1; off >>= 1)
                mx = fmaxf(mx, __shfl_xor(mx, off));
            float mn = fmaxf(mrow[r], mx);
            alpha[r] = __expf(mrow[r] - mn);
            mrow[r] = mn;
            float sum = 0.f;
            #pragma unroll
            for (int nt = 0; nt < 4; nt++) {
                float pv = __expf(S[nt][r] * 0.125f - mn);
                p[nt][r] = pv; sum += pv;
            }
            #pragma unroll
            for (int off = 8; off >= 1; off >>= 1)
                sum += __shfl_xor(sum, off);
            lrow[r] = lrow[r] * alpha[r] + sum;
        }

        // P -> LDS (A-layout round trip; wave-local rows)
        #pragma unroll
        for (int nt = 0; nt < 4; nt++)
            #pragma unroll
            for (int r = 0; r < 4; r++)
                p_s[(wq*16 + lq*4 + r) * PSTR + nt*16 + lm] = f2b(p[nt][r]);

        // O rescale
        #pragma unroll
        for (int nt = 0; nt < 4; nt++)
            #pragma unroll
            for (int r = 0; r < 4; r++)
                O[nt][r] *= alpha[r];

        // PV: A = P[q][kpos], B = V^T[d][kpos]
        #pragma unroll
        for (int ks = 0; ks < 2; ks++) {
            bf16x8 ap = *(const bf16x8*)&p_s[(wq*16 + lm) * PSTR + ks*32 + lq*8];
            #pragma unroll
            for (int nt = 0; nt < 4; nt++) {
                bf16x8 bv = *(const bf16x8*)&vt_s[(nt*16 + lm) * VSTR + ks*32 + lq*8];
                O[nt] = __builtin_amdgcn_mfma_f32_16x16x32_bf16(ap, bv, O[nt], 0, 0, 0);
            }
        }
        __syncthreads();
    }

    // write O/l into this block's Q slots
    #pragma unroll
    for (int r = 0; r < 4; r++) {
        float inv = 1.f / lrow[r];
        uint16_t* dst = qk + (rowbase + qb*64 + wq*16 + lq*4 + r) * QKLD + hcol;
        #pragma unroll
        for (int nt = 0; nt < 4; nt++)
            dst[nt*16 + lm] = f2b(O[nt][r] * inv);
    }
}

extern "C" void kernel_launch(void* const* d_in, const int* in_sizes, int n_in,
                              void* d_out, int out_size, void* d_ws, size_t ws_size,
                              hipStream_t stream) {
    const float* x      = (const float*)d_in[0];   // [8192][768] fp32
    const float* ln1_g  = (const float*)d_in[1];
    const float* ln1_b  = (const float*)d_in[2];
    const float* ln2_g  = (const float*)d_in[3];
    const float* ln2_b  = (const float*)d_in[4];
    const float* w_qkv  = (const float*)d_in[5];   // [768][2304]
    const float* w_out  = (const float*)d_in[6];   // [768][768]
    const float* b_out  = (const float*)d_in[7];
    const float* w_ff1  = (const float*)d_in[8];   // [768][3072]
    const float* b_ff1  = (const float*)d_in[9];
    const float* w_ff2  = (const float*)d_in[10];  // [3072][768]
    const float* b_ff2  = (const float*)d_in[11];
    float* out = (float*)d_out;                    // [8192][768] fp32

    // ws layout (uint16 elements), peak 64.5 MB (proven safe)
    uint16_t* ws  = (uint16_t*)d_ws;
    uint16_t* qk  = ws;                            // [8192][1536] Q,K
    uint16_t* ffc = ws;                            // [8192][1536] (reuses dead qk)
    uint16_t* vT  = ws + (size_t)12582912;         // [8][768][1024]
    uint16_t* h   = ws + (size_t)18874368;         // [8192][768]
    uint16_t* WqT = ws + (size_t)25165824;         // [2304][768]
    uint16_t* WoT = ws + (size_t)26935296;         // [768][768]
    uint16_t* W1T = ws + (size_t)27525120;         // [3072][768]
    uint16_t* W2T = ws + (size_t)29884416;         // [768][3072]

    dim3 tb(32, 8);
    hipLaunchKernelGGL(transpose_convert, dim3(QKVN/32, DIM/32), tb, 0, stream, w_qkv, WqT, DIM, QKVN);
    hipLaunchKernelGGL(transpose_convert, dim3(DIM/32,  DIM/32), tb, 0, stream, w_out, WoT, DIM, DIM);
    hipLaunchKernelGGL(transpose_convert, dim3(FFDIM/32, DIM/32), tb, 0, stream, w_ff1, W1T, DIM, FFDIM);
    hipLaunchKernelGGL(transpose_convert, dim3(DIM/32, FFDIM/32), tb, 0, stream, w_ff2, W2T, FFDIM, DIM);

    // h = LN1(x)
    hipLaunchKernelGGL(ln_naive, dim3(TOK), dim3(64), 0, stream, x, ln1_g, ln1_b, h);
    // qk (+vT split) = h @ w_qkv
    hipLaunchKernelGGL((gemm_bt<false, false, false, false, true>), dim3(QKVN/128, TOK/128), dim3(256), 0, stream,
                       h, WqT, qk, nullptr, 0, nullptr, QKVN, DIM, DIM, DIM, QKLD, vT);
    // attention in-place (O -> Q slots of qk)
    hipLaunchKernelGGL(flash_mfma, dim3(SEQ/64, HEADS, BATCH), dim3(256), 0, stream, qk, vT);
    // d_out(fp32) = x + attnO @ w_out + b_out
    hipLaunchKernelGGL((gemm_bt<true, false, true, true, false>), dim3(DIM/128, TOK/128), dim3(256), 0, stream,
                       qk, WoT, out, b_out, 0, x, DIM, INNER, QKLD, DIM, DIM, nullptr);
    // h = LN2(d_out)
    hipLaunchKernelGGL(ln_naive, dim3(TOK), dim3(64), 0, stream, out, ln2_g, ln2_b, h);
    // FFN in two hidden chunks of 1536 (ffc reuses dead qk region)
    for (int c = 0; c < 2; c++) {
        hipLaunchKernelGGL((gemm_bt<true, true, false, false, false>), dim3(1536/128, TOK/128), dim3(256), 0, stream,
                           h, W1T + (size_t)c*1536*DIM, ffc, b_ff1, c*1536, nullptr,
                           1536, DIM, DIM, DIM, 1536, nullptr);
        if (c == 0) {
            hipLaunchKernelGGL((gemm_bt<true, false, true, true, false>), dim3(DIM/128, TOK/128), dim3(256), 0, stream,
                               ffc, W2T + (size_t)c*1536, out, b_ff2, 0, out,
                               DIM, 1536, 1536, FFDIM, DIM, nullptr);
        } else {
            hipLaunchKernelGGL((gemm_bt<false, false, true, true, false>), dim3(DIM/128, TOK/128), dim3(256), 0, stream,
                               ffc, W2T + (size_t)c*1536, out, nullptr, 0, out,
                               DIM, 1536, 1536, FFDIM, DIM, nullptr);
        }
    }
}